// Round 1
// baseline (673.728 us; speedup 1.0000x reference)
//
#include <hip/hip_runtime.h>
#include <hip/hip_bf16.h>
#include <stdint.h>

// Problem constants (fixed by the reference): B=2, T=4096, D=1024, H=16, HS=64.
// Pipeline: cvt(x,W,b) -> GEMM qkv (bf16 MFMA) -> flash attention (bf16 MFMA,
// online softmax, causal) -> GEMM out proj (bf16 MFMA, fp32 out).

typedef __bf16 bf16x8 __attribute__((ext_vector_type(8)));
typedef float f32x4 __attribute__((ext_vector_type(4)));
typedef __attribute__((address_space(1))) void gvoid_t;
typedef __attribute__((address_space(3))) void lvoid_t;

using hbf = __hip_bfloat16;

static __device__ __forceinline__ void gload_lds16(const void* g, void* l) {
  // async global->LDS, 16B per lane; LDS dest is wave-uniform base + lane*16
  __builtin_amdgcn_global_load_lds((gvoid_t*)g, (lvoid_t*)l, 16, 0, 0);
}

// ---------------- converters ----------------

__global__ void k_cvt_x(const float* __restrict__ x, hbf* __restrict__ xb) {
  int i = (blockIdx.x * 256 + threadIdx.x) * 4;
  float4 v = *reinterpret_cast<const float4*>(x + i);
  hbf h[4] = {__float2bfloat16(v.x), __float2bfloat16(v.y),
              __float2bfloat16(v.z), __float2bfloat16(v.w)};
  *reinterpret_cast<ushort4*>(xb + i) = *reinterpret_cast<ushort4*>(h);
}

// Wt[r][d], r=(m,h,e): transposed per-head weights, q scaled by 1/8
__global__ void k_cvt_w(const float* __restrict__ Wq, const float* __restrict__ Wk,
                        const float* __restrict__ Wv, hbf* __restrict__ Wt) {
  int idx = blockIdx.x * 256 + threadIdx.x;   // 3072*1024 total
  int d = idx & 1023, r = idx >> 10;
  int m = r >> 10, rem = r & 1023;
  int h = rem >> 6, e = rem & 63;
  const float* W = (m == 0) ? Wq : (m == 1) ? Wk : Wv;
  float v = W[(h << 10 | d) * 64 + e];
  if (m == 0) v *= 0.125f;
  Wt[idx] = __float2bfloat16(v);
}

__global__ void k_cvt_bias(const float* __restrict__ bq, const float* __restrict__ bk,
                           const float* __restrict__ bv, float* __restrict__ biasc) {
  int r = blockIdx.x * 256 + threadIdx.x;     // 0..3071
  int m = r >> 10, rem = r & 1023;
  const float* bsrc = (m == 0) ? bq : (m == 1) ? bk : bv;
  float v = bsrc[rem];
  if (m == 0) v *= 0.125f;
  biasc[r] = v;
}

__global__ void k_cvt_wp(const float* __restrict__ Wp, hbf* __restrict__ Wpt) {
  int idx = blockIdx.x * 256 + threadIdx.x;   // 1024*1024
  int o = idx >> 10, d = idx & 1023;
  Wpt[idx] = __float2bfloat16(Wp[(d << 10) + o]);  // Wpt[o][d] = Wp[d][o]
}

// ---------------- QKV projection GEMM ----------------
// C[8192][3072] = xb[8192][1024] @ Wt^T ; scatter to qkv[3][32][4096][64] bf16

__global__ __launch_bounds__(256) void k_gemm_qkv(
    const hbf* __restrict__ A, const hbf* __restrict__ Bw,
    const float* __restrict__ biasc, hbf* __restrict__ qkv) {
  __shared__ hbf sA[128 * 64];
  __shared__ hbf sB[128 * 64];
  const int tid = threadIdx.x;
  const int lane = tid & 63, wid = tid >> 6;
  const int m0 = blockIdx.x * 128, n0 = blockIdx.y * 128;
  const int g = lane >> 4, cl = lane & 15;

  const f32x4 fz = {0.f, 0.f, 0.f, 0.f};
  f32x4 acc[4][4];
#pragma unroll
  for (int a = 0; a < 4; ++a)
#pragma unroll
    for (int b = 0; b < 4; ++b) acc[a][b] = fz;

  const int srow = wid * 32 + (lane >> 3);
  const int scol = (lane & 7) * 8;

  for (int kt = 0; kt < 16; ++kt) {
    const int k0 = kt * 64;
#pragma unroll
    for (int t = 0; t < 4; ++t) {
      const int r = srow + t * 8;
      gload_lds16(A + (size_t)(m0 + r) * 1024 + k0 + scol, sA + (wid * 32 + t * 8) * 64);
      gload_lds16(Bw + (size_t)(n0 + r) * 1024 + k0 + scol, sB + (wid * 32 + t * 8) * 64);
    }
    __syncthreads();   // drains vmcnt (global_load_lds) + orders LDS
#pragma unroll
    for (int ks = 0; ks < 2; ++ks) {
      const int ko = ks * 32 + g * 8;
      bf16x8 af[4], bfr[4];
#pragma unroll
      for (int rt = 0; rt < 4; ++rt)
        af[rt] = *reinterpret_cast<const bf16x8*>(sA + ((wid & 1) * 64 + rt * 16 + cl) * 64 + ko);
#pragma unroll
      for (int ct = 0; ct < 4; ++ct)
        bfr[ct] = *reinterpret_cast<const bf16x8*>(sB + ((wid >> 1) * 64 + ct * 16 + cl) * 64 + ko);
#pragma unroll
      for (int rt = 0; rt < 4; ++rt)
#pragma unroll
        for (int ct = 0; ct < 4; ++ct)
          acc[rt][ct] = __builtin_amdgcn_mfma_f32_16x16x32_bf16(af[rt], bfr[ct], acc[rt][ct], 0, 0, 0);
    }
    __syncthreads();
  }

#pragma unroll
  for (int rt = 0; rt < 4; ++rt)
#pragma unroll
    for (int ct = 0; ct < 4; ++ct) {
      const int colg = n0 + (wid >> 1) * 64 + ct * 16 + cl;
      const int mi = colg >> 10, rem = colg & 1023;
      const int h = rem >> 6, e = rem & 63;
      const float bi = biasc[colg];
#pragma unroll
      for (int i = 0; i < 4; ++i) {
        const int rowg = m0 + (wid & 1) * 64 + rt * 16 + g * 4 + i;
        const int b = rowg >> 12, t = rowg & 4095;
        qkv[(((size_t)mi * 32 + b * 16 + h) * 4096 + t) * 64 + e] =
            __float2bfloat16(acc[rt][ct][i] + bi);
      }
    }
}

// ---------------- flash attention ----------------
// grid (T/64, B*H); 4 waves x 16 q-rows; KV tiles of 64; causal.

__global__ __launch_bounds__(256) void k_flash(
    const hbf* __restrict__ qkv, hbf* __restrict__ attn) {
  __shared__ hbf sK[64 * 72];        // K tile [s][e], row stride 72 (pad 8)
  __shared__ hbf sVt[64 * 72];       // V^T tile [e][s]
  __shared__ hbf sP[4 * 16 * 72];    // per-wave P [qr][s]
  const int tid = threadIdx.x, lane = tid & 63, wid = tid >> 6;
  const int g = lane >> 4, cl = lane & 15;
  const int qt = blockIdx.x, bh = blockIdx.y;
  const int q0 = qt * 64;
  const hbf* Q  = qkv + (size_t)bh * (4096 * 64);
  const hbf* Kp = qkv + (size_t)(32 + bh) * (4096 * 64);
  const hbf* Vp = qkv + (size_t)(64 + bh) * (4096 * 64);
  const float NEG_INF = -__builtin_inff();

  bf16x8 aq[2];  // Q rows of this wave, already scaled by 1/8 upstream
#pragma unroll
  for (int ks = 0; ks < 2; ++ks)
    aq[ks] = *reinterpret_cast<const bf16x8*>(Q + (size_t)(q0 + wid * 16 + cl) * 64 + ks * 32 + g * 8);

  const f32x4 fz = {0.f, 0.f, 0.f, 0.f};
  f32x4 accO[4];
#pragma unroll
  for (int nt = 0; nt < 4; ++nt) accO[nt] = fz;
  float mrow[4], lrow[4];
#pragma unroll
  for (int i = 0; i < 4; ++i) { mrow[i] = NEG_INF; lrow[i] = 0.f; }

  for (int j = 0; j <= qt; ++j) {
    __syncthreads();  // previous tile's reads done before overwrite
#pragma unroll
    for (int p = 0; p < 2; ++p) {
      const int r = p * 32 + (tid >> 3);
      const int c = (tid & 7) * 8;
      bf16x8 kv = *reinterpret_cast<const bf16x8*>(Kp + ((size_t)j * 64 + r) * 64 + c);
      *reinterpret_cast<bf16x8*>(&sK[r * 72 + c]) = kv;
      bf16x8 vv = *reinterpret_cast<const bf16x8*>(Vp + ((size_t)j * 64 + r) * 64 + c);
#pragma unroll
      for (int u = 0; u < 8; ++u)
        reinterpret_cast<__bf16*>(sVt)[(c + u) * 72 + r] = vv[u];
    }
    __syncthreads();

    // S = Q K^T (scale pre-folded into Q)
    f32x4 accS[4];
#pragma unroll
    for (int nt = 0; nt < 4; ++nt) {
      f32x4 s = fz;
#pragma unroll
      for (int ks = 0; ks < 2; ++ks) {
        bf16x8 bk = *reinterpret_cast<const bf16x8*>(&sK[(nt * 16 + cl) * 72 + ks * 32 + g * 8]);
        s = __builtin_amdgcn_mfma_f32_16x16x32_bf16(aq[ks], bk, s, 0, 0, 0);
      }
      accS[nt] = s;
    }
    if (j == qt) {  // causal mask on diagonal tile
#pragma unroll
      for (int nt = 0; nt < 4; ++nt) {
        const int sc = nt * 16 + cl;
#pragma unroll
        for (int i = 0; i < 4; ++i)
          if (sc > wid * 16 + g * 4 + i) accS[nt][i] = NEG_INF;
      }
    }

    // online softmax: row reductions across the 16-lane group
    float corr[4];
#pragma unroll
    for (int i = 0; i < 4; ++i) {
      float v = fmaxf(fmaxf(accS[0][i], accS[1][i]), fmaxf(accS[2][i], accS[3][i]));
      v = fmaxf(v, __shfl_xor(v, 1));
      v = fmaxf(v, __shfl_xor(v, 2));
      v = fmaxf(v, __shfl_xor(v, 4));
      v = fmaxf(v, __shfl_xor(v, 8));
      const float mn = fmaxf(mrow[i], v);
      corr[i] = __expf(mrow[i] - mn);
      mrow[i] = mn;
    }
    float rs[4] = {0.f, 0.f, 0.f, 0.f};
#pragma unroll
    for (int nt = 0; nt < 4; ++nt)
#pragma unroll
      for (int i = 0; i < 4; ++i) {
        const float p = __expf(accS[nt][i] - mrow[i]);
        rs[i] += p;
        sP[(wid * 16 + g * 4 + i) * 72 + nt * 16 + cl] = __float2bfloat16(p);
      }
#pragma unroll
    for (int i = 0; i < 4; ++i) {
      float v = rs[i];
      v += __shfl_xor(v, 1);
      v += __shfl_xor(v, 2);
      v += __shfl_xor(v, 4);
      v += __shfl_xor(v, 8);
      lrow[i] = lrow[i] * corr[i] + v;
    }
#pragma unroll
    for (int nt = 0; nt < 4; ++nt)
#pragma unroll
      for (int i = 0; i < 4; ++i) accO[nt][i] *= corr[i];

    // same-wave LDS write->read: DS pipe is in-order per wave; stop compiler reorder
    asm volatile("s_waitcnt lgkmcnt(0)" ::: "memory");

    // O += P V
#pragma unroll
    for (int ks = 0; ks < 2; ++ks) {
      bf16x8 ap = *reinterpret_cast<const bf16x8*>(&sP[(wid * 16 + cl) * 72 + ks * 32 + g * 8]);
#pragma unroll
      for (int nt = 0; nt < 4; ++nt) {
        bf16x8 bv = *reinterpret_cast<const bf16x8*>(&sVt[(nt * 16 + cl) * 72 + ks * 32 + g * 8]);
        accO[nt] = __builtin_amdgcn_mfma_f32_16x16x32_bf16(ap, bv, accO[nt], 0, 0, 0);
      }
    }
  }

#pragma unroll
  for (int nt = 0; nt < 4; ++nt) {
    const int e = nt * 16 + cl;
#pragma unroll
    for (int i = 0; i < 4; ++i) {
      const int qrow = q0 + wid * 16 + g * 4 + i;
      attn[((size_t)(bh >> 4) * 4096 + qrow) * 1024 + (bh & 15) * 64 + e] =
          __float2bfloat16(accO[nt][i] / lrow[i]);
    }
  }
}

// ---------------- output projection GEMM ----------------
// out[8192][1024] = attn[8192][1024] @ Wpt^T + bp, fp32 out

__global__ __launch_bounds__(256) void k_gemm_out(
    const hbf* __restrict__ A, const hbf* __restrict__ Bw,
    const float* __restrict__ bp, float* __restrict__ out) {
  __shared__ hbf sA[128 * 64];
  __shared__ hbf sB[128 * 64];
  const int tid = threadIdx.x;
  const int lane = tid & 63, wid = tid >> 6;
  const int m0 = blockIdx.x * 128, n0 = blockIdx.y * 128;
  const int g = lane >> 4, cl = lane & 15;

  const f32x4 fz = {0.f, 0.f, 0.f, 0.f};
  f32x4 acc[4][4];
#pragma unroll
  for (int a = 0; a < 4; ++a)
#pragma unroll
    for (int b = 0; b < 4; ++b) acc[a][b] = fz;

  const int srow = wid * 32 + (lane >> 3);
  const int scol = (lane & 7) * 8;

  for (int kt = 0; kt < 16; ++kt) {
    const int k0 = kt * 64;
#pragma unroll
    for (int t = 0; t < 4; ++t) {
      const int r = srow + t * 8;
      gload_lds16(A + (size_t)(m0 + r) * 1024 + k0 + scol, sA + (wid * 32 + t * 8) * 64);
      gload_lds16(Bw + (size_t)(n0 + r) * 1024 + k0 + scol, sB + (wid * 32 + t * 8) * 64);
    }
    __syncthreads();
#pragma unroll
    for (int ks = 0; ks < 2; ++ks) {
      const int ko = ks * 32 + g * 8;
      bf16x8 af[4], bfr[4];
#pragma unroll
      for (int rt = 0; rt < 4; ++rt)
        af[rt] = *reinterpret_cast<const bf16x8*>(sA + ((wid & 1) * 64 + rt * 16 + cl) * 64 + ko);
#pragma unroll
      for (int ct = 0; ct < 4; ++ct)
        bfr[ct] = *reinterpret_cast<const bf16x8*>(sB + ((wid >> 1) * 64 + ct * 16 + cl) * 64 + ko);
#pragma unroll
      for (int rt = 0; rt < 4; ++rt)
#pragma unroll
        for (int ct = 0; ct < 4; ++ct)
          acc[rt][ct] = __builtin_amdgcn_mfma_f32_16x16x32_bf16(af[rt], bfr[ct], acc[rt][ct], 0, 0, 0);
    }
    __syncthreads();
  }

#pragma unroll
  for (int rt = 0; rt < 4; ++rt)
#pragma unroll
    for (int ct = 0; ct < 4; ++ct) {
      const int colg = n0 + (wid >> 1) * 64 + ct * 16 + cl;
      const float bi = bp[colg];
#pragma unroll
      for (int i = 0; i < 4; ++i) {
        const int rowg = m0 + (wid & 1) * 64 + rt * 16 + g * 4 + i;
        out[(size_t)rowg * 1024 + colg] = acc[rt][ct][i] + bi;
      }
    }
}

// ---------------- launcher ----------------

extern "C" void kernel_launch(void* const* d_in, const int* in_sizes, int n_in,
                              void* d_out, int out_size, void* d_ws, size_t ws_size,
                              hipStream_t stream) {
  const float* x  = (const float*)d_in[0];
  const float* Wq = (const float*)d_in[1];
  const float* Wk = (const float*)d_in[2];
  const float* Wv = (const float*)d_in[3];
  const float* bq = (const float*)d_in[4];
  const float* bk = (const float*)d_in[5];
  const float* bv = (const float*)d_in[6];
  const float* Wp = (const float*)d_in[7];
  const float* bp = (const float*)d_in[8];
  float* out = (float*)d_out;

  char* ws = (char*)d_ws;
  hbf*   xb    = (hbf*)ws;                                   // 16 MiB (reused as attn_out)
  hbf*   Wt    = (hbf*)(ws + 16777216);                      // 6 MiB
  hbf*   Wpt   = (hbf*)(ws + 16777216 + 6291456);            // 2 MiB
  float* biasc = (float*)(ws + 16777216 + 6291456 + 2097152);// 12 KiB (+pad)
  hbf*   qkv   = (hbf*)(ws + 16777216 + 6291456 + 2097152 + 16384); // 48 MiB
  hbf*   attn  = xb;  // safe: GEMM1 consumed xb before flash writes

  k_cvt_x   <<<8192,  256, 0, stream>>>(x, xb);
  k_cvt_w   <<<12288, 256, 0, stream>>>(Wq, Wk, Wv, Wt);
  k_cvt_bias<<<12,    256, 0, stream>>>(bq, bk, bv, biasc);
  k_cvt_wp  <<<4096,  256, 0, stream>>>(Wp, Wpt);

  dim3 g1(64, 24); k_gemm_qkv<<<g1, 256, 0, stream>>>(xb, Wt, biasc, qkv);
  dim3 g2(64, 32); k_flash   <<<g2, 256, 0, stream>>>(qkv, attn);
  dim3 g3(64, 8);  k_gemm_out<<<g3, 256, 0, stream>>>(attn, Wpt, bp, out);
}

// Round 3
// 360.301 us; speedup vs baseline: 1.8699x; 1.8699x over previous
//
#include <hip/hip_runtime.h>
#include <hip/hip_bf16.h>
#include <stdint.h>

// B=2, T=4096, D=1024, H=16, HS=64. Pipeline:
// cvt -> GEMM qkv (bf16 MFMA) -> flash attn (dbuf LDS, swizzled K + swizzled
// transposed V, exp2 softmax, T14 split V staging) -> GEMM out proj.

typedef __bf16 bf16x8 __attribute__((ext_vector_type(8)));
typedef float f32x4 __attribute__((ext_vector_type(4)));
typedef __attribute__((address_space(1))) void gvoid_t;
typedef __attribute__((address_space(3))) void lvoid_t;

using hbf = __hip_bfloat16;

#define QSCALE (0.125f * 1.44269504088896f)  // 1/sqrt(HS) * log2(e)

static __device__ __forceinline__ void gload_lds16(const void* g, void* l) {
  __builtin_amdgcn_global_load_lds((gvoid_t*)g, (lvoid_t*)l, 16, 0, 0);
}

static __device__ __forceinline__ __bf16 f2b(float x) {
  hbf h = __float2bfloat16(x);
  return *reinterpret_cast<__bf16*>(&h);
}

// ---------------- converters ----------------

__global__ void k_cvt_x(const float* __restrict__ x, hbf* __restrict__ xb) {
  int i = (blockIdx.x * 256 + threadIdx.x) * 4;
  float4 v = *reinterpret_cast<const float4*>(x + i);
  hbf h[4] = {__float2bfloat16(v.x), __float2bfloat16(v.y),
              __float2bfloat16(v.z), __float2bfloat16(v.w)};
  *reinterpret_cast<ushort4*>(xb + i) = *reinterpret_cast<ushort4*>(h);
}

__global__ void k_cvt_w(const float* __restrict__ Wq, const float* __restrict__ Wk,
                        const float* __restrict__ Wv, hbf* __restrict__ Wt) {
  int idx = blockIdx.x * 256 + threadIdx.x;   // 3072*1024
  int d = idx & 1023, r = idx >> 10;
  int m = r >> 10, rem = r & 1023;
  int h = rem >> 6, e = rem & 63;
  const float* W = (m == 0) ? Wq : (m == 1) ? Wk : Wv;
  float v = W[(h << 10 | d) * 64 + e];
  if (m == 0) v *= QSCALE;
  Wt[idx] = __float2bfloat16(v);
}

__global__ void k_cvt_bias(const float* __restrict__ bq, const float* __restrict__ bk,
                           const float* __restrict__ bv, float* __restrict__ biasc) {
  int r = blockIdx.x * 256 + threadIdx.x;     // 0..3071
  int m = r >> 10, rem = r & 1023;
  const float* bsrc = (m == 0) ? bq : (m == 1) ? bk : bv;
  float v = bsrc[rem];
  if (m == 0) v *= QSCALE;
  biasc[r] = v;
}

__global__ void k_cvt_wp(const float* __restrict__ Wp, hbf* __restrict__ Wpt) {
  int idx = blockIdx.x * 256 + threadIdx.x;   // 1024*1024
  int o = idx >> 10, d = idx & 1023;
  Wpt[idx] = __float2bfloat16(Wp[(d << 10) + o]);
}

// ---------------- QKV projection GEMM ----------------

__global__ __launch_bounds__(256) void k_gemm_qkv(
    const hbf* __restrict__ A, const hbf* __restrict__ Bw,
    const float* __restrict__ biasc, hbf* __restrict__ qkv) {
  __shared__ __align__(16) hbf sA[128 * 64];
  __shared__ __align__(16) hbf sB[128 * 64];
  const int tid = threadIdx.x;
  const int lane = tid & 63, wid = tid >> 6;
  const int m0 = blockIdx.x * 128, n0 = blockIdx.y * 128;
  const int g = lane >> 4, cl = lane & 15;

  const f32x4 fz = {0.f, 0.f, 0.f, 0.f};
  f32x4 acc[4][4];
#pragma unroll
  for (int a = 0; a < 4; ++a)
#pragma unroll
    for (int b = 0; b < 4; ++b) acc[a][b] = fz;

  const int srow = wid * 32 + (lane >> 3);
  const int scol = (lane & 7) * 8;

  for (int kt = 0; kt < 16; ++kt) {
    const int k0 = kt * 64;
#pragma unroll
    for (int t = 0; t < 4; ++t) {
      const int r = srow + t * 8;
      gload_lds16(A + (size_t)(m0 + r) * 1024 + k0 + scol, sA + (wid * 32 + t * 8) * 64);
      gload_lds16(Bw + (size_t)(n0 + r) * 1024 + k0 + scol, sB + (wid * 32 + t * 8) * 64);
    }
    __syncthreads();
#pragma unroll
    for (int ks = 0; ks < 2; ++ks) {
      const int ko = ks * 32 + g * 8;
      bf16x8 af[4], bfr[4];
#pragma unroll
      for (int rt = 0; rt < 4; ++rt)
        af[rt] = *reinterpret_cast<const bf16x8*>(sA + ((wid & 1) * 64 + rt * 16 + cl) * 64 + ko);
#pragma unroll
      for (int ct = 0; ct < 4; ++ct)
        bfr[ct] = *reinterpret_cast<const bf16x8*>(sB + ((wid >> 1) * 64 + ct * 16 + cl) * 64 + ko);
#pragma unroll
      for (int rt = 0; rt < 4; ++rt)
#pragma unroll
        for (int ct = 0; ct < 4; ++ct)
          acc[rt][ct] = __builtin_amdgcn_mfma_f32_16x16x32_bf16(af[rt], bfr[ct], acc[rt][ct], 0, 0, 0);
    }
    __syncthreads();
  }

#pragma unroll
  for (int rt = 0; rt < 4; ++rt)
#pragma unroll
    for (int ct = 0; ct < 4; ++ct) {
      const int colg = n0 + (wid >> 1) * 64 + ct * 16 + cl;
      const int mi = colg >> 10, rem = colg & 1023;
      const int h = rem >> 6, e = rem & 63;
      const float bi = biasc[colg];
#pragma unroll
      for (int i = 0; i < 4; ++i) {
        const int rowg = m0 + (wid & 1) * 64 + rt * 16 + g * 4 + i;
        const int b = rowg >> 12, t = rowg & 4095;
        qkv[(((size_t)mi * 32 + b * 16 + h) * 4096 + t) * 64 + e] =
            __float2bfloat16(acc[rt][ct][i] + bi);
      }
    }
}

// ---------------- flash attention ----------------
// grid (bh=32, 64); qt = 63 - blockIdx.y. 4 waves x 16 q-rows, KV tiles of 64.
// K: XOR-swizzled rows via global_load_lds (chunk c of row r stored at c^(r&7)).
// V: transposed [e][s] with chunk swizzle (s>>3)^(e&7)^((e>>3)&7); staged
// global->reg (coalesced) at loop top, reg->LDS scalar writes after PV
// (conflict-free: banks span lane bits {0,1,3,4,5}).
// Double-buffered, one barrier/iter; exp2-domain softmax.

__global__ __launch_bounds__(256) void k_flash(
    const hbf* __restrict__ qkv, hbf* __restrict__ attn) {
  __shared__ __align__(16) __bf16 sK[2][64 * 64];
  __shared__ __align__(16) __bf16 sV[2][64 * 64];
  __shared__ __align__(16) __bf16 sP[4][16 * 72];
  const int tid = threadIdx.x, lane = tid & 63, wid = tid >> 6;
  const int g = lane >> 4, cl = lane & 15;
  const int bh = blockIdx.x;
  const int qt = (int)gridDim.y - 1 - (int)blockIdx.y;
  const int q0 = qt * 64;
  const hbf* Q  = qkv + (size_t)bh * (4096 * 64);
  const hbf* Kp = qkv + (size_t)(32 + bh) * (4096 * 64);
  const hbf* Vp = qkv + (size_t)(64 + bh) * (4096 * 64);
  const float NEG_INF = -__builtin_inff();

  // K staging: lane covers row wid*16+(lane>>3) (+8 on 2nd call), source chunk
  // pre-swizzled so linear DMA dest lands XOR-swizzled (both-sides rule #21).
  const int koff = (wid * 16 + (lane >> 3)) * 64 + (((lane & 7) ^ (lane >> 3)) * 8);
  // V staging: thread t loads V[r=t>>2][c0=(t&3)*16 .. +16] (coalesced).
  const int vr = tid >> 2, vc0 = (tid & 3) * 16;
  const int vgoff = vr * 64 + vc0;

  bf16x8 aq[2];
#pragma unroll
  for (int ks = 0; ks < 2; ++ks)
    aq[ks] = *reinterpret_cast<const bf16x8*>(Q + (size_t)(q0 + wid * 16 + cl) * 64 + ks * 32 + g * 8);

  const f32x4 fz = {0.f, 0.f, 0.f, 0.f};
  f32x4 accO[4];
#pragma unroll
  for (int nt = 0; nt < 4; ++nt) accO[nt] = fz;
  float mrow[4], lrow[4];
#pragma unroll
  for (int i = 0; i < 4; ++i) { mrow[i] = NEG_INF; lrow[i] = 0.f; }

  // transpose+swizzle scatter of one thread's 16 V values into Vt[e][s]
  auto vwrite = [&](__bf16* dst, bf16x8 a, bf16x8 b) {
#pragma unroll
    for (int u = 0; u < 8; ++u) {
      const int e = vc0 + u;
      dst[e * 64 + (((vr >> 3) ^ (e & 7) ^ ((e >> 3) & 7)) * 8) + (vr & 7)] = a[u];
    }
#pragma unroll
    for (int u = 8; u < 16; ++u) {
      const int e = vc0 + u;
      dst[e * 64 + (((vr >> 3) ^ (e & 7) ^ ((e >> 3) & 7)) * 8) + (vr & 7)] = b[u - 8];
    }
  };

  // prologue: stage tile 0 into buf 0
  gload_lds16(Kp + koff,       &sK[0][wid * 1024]);
  gload_lds16(Kp + koff + 512, &sK[0][wid * 1024 + 512]);
  {
    bf16x8 a = *reinterpret_cast<const bf16x8*>(Vp + vgoff);
    bf16x8 b = *reinterpret_cast<const bf16x8*>(Vp + vgoff + 8);
    vwrite(sV[0], a, b);
  }
  __syncthreads();

  int buf = 0;
  for (int j = 0; j <= qt; ++j) {
    bf16x8 va, vb;
    if (j < qt) {  // prefetch tile j+1: K -> LDS DMA, V -> regs (T14 split)
      const hbf* Kg = Kp + (size_t)(j + 1) * 4096;
      gload_lds16(Kg + koff,       &sK[buf ^ 1][wid * 1024]);
      gload_lds16(Kg + koff + 512, &sK[buf ^ 1][wid * 1024 + 512]);
      const hbf* Vg = Vp + (size_t)(j + 1) * 4096 + vgoff;
      va = *reinterpret_cast<const bf16x8*>(Vg);
      vb = *reinterpret_cast<const bf16x8*>(Vg + 8);
    }

    // S = Q K^T from swizzled sK
    const __bf16* sKb = sK[buf];
    f32x4 accS[4];
#pragma unroll
    for (int nt = 0; nt < 4; ++nt) {
      f32x4 s = fz;
#pragma unroll
      for (int ks = 0; ks < 2; ++ks) {
        bf16x8 bk = *reinterpret_cast<const bf16x8*>(
            sKb + (nt * 16 + cl) * 64 + (((ks * 4 + g) ^ (cl & 7)) * 8));
        s = __builtin_amdgcn_mfma_f32_16x16x32_bf16(aq[ks], bk, s, 0, 0, 0);
      }
      accS[nt] = s;
    }
    if (j == qt) {  // causal mask on diagonal tile
#pragma unroll
      for (int nt = 0; nt < 4; ++nt) {
        const int sc = nt * 16 + cl;
#pragma unroll
        for (int i = 0; i < 4; ++i)
          if (sc > wid * 16 + g * 4 + i) accS[nt][i] = NEG_INF;
      }
    }

    // online softmax (exp2 domain; scale*log2e folded into Q upstream)
    float corr[4];
#pragma unroll
    for (int i = 0; i < 4; ++i) {
      float v = fmaxf(fmaxf(accS[0][i], accS[1][i]), fmaxf(accS[2][i], accS[3][i]));
      v = fmaxf(v, __shfl_xor(v, 1));
      v = fmaxf(v, __shfl_xor(v, 2));
      v = fmaxf(v, __shfl_xor(v, 4));
      v = fmaxf(v, __shfl_xor(v, 8));
      const float mn = fmaxf(mrow[i], v);
      corr[i] = __builtin_amdgcn_exp2f(mrow[i] - mn);
      mrow[i] = mn;
    }
    float rs[4] = {0.f, 0.f, 0.f, 0.f};
#pragma unroll
    for (int nt = 0; nt < 4; ++nt)
#pragma unroll
      for (int i = 0; i < 4; ++i) {
        const float p = __builtin_amdgcn_exp2f(accS[nt][i] - mrow[i]);
        rs[i] += p;
        sP[wid][(g * 4 + i) * 72 + nt * 16 + cl] = f2b(p);
      }
#pragma unroll
    for (int i = 0; i < 4; ++i) {
      float v = rs[i];
      v += __shfl_xor(v, 1);
      v += __shfl_xor(v, 2);
      v += __shfl_xor(v, 4);
      v += __shfl_xor(v, 8);
      lrow[i] = lrow[i] * corr[i] + v;
    }
#pragma unroll
    for (int nt = 0; nt < 4; ++nt)
#pragma unroll
      for (int i = 0; i < 4; ++i) accO[nt][i] *= corr[i];

    // O += P V ; B-fragment from swizzled Vt[e][s]
    const __bf16* sVb = sV[buf];
#pragma unroll
    for (int ks = 0; ks < 2; ++ks) {
      bf16x8 ap = *reinterpret_cast<const bf16x8*>(&sP[wid][cl * 72 + ks * 32 + g * 8]);
#pragma unroll
      for (int nt = 0; nt < 4; ++nt) {
        const int e = nt * 16 + cl;
        const int chunk = (ks * 4 + g) ^ (cl & 7) ^ ((2 * nt + (cl >> 3)) & 7);
        bf16x8 bv = *reinterpret_cast<const bf16x8*>(sVb + e * 64 + chunk * 8);
        accO[nt] = __builtin_amdgcn_mfma_f32_16x16x32_bf16(ap, bv, accO[nt], 0, 0, 0);
      }
    }

    if (j < qt) vwrite(sV[buf ^ 1], va, vb);  // loads had QK+softmax+PV to land
    __syncthreads();  // drains K DMA + V writes; all waves done with buf
    buf ^= 1;
  }

#pragma unroll
  for (int nt = 0; nt < 4; ++nt) {
    const int e = nt * 16 + cl;
#pragma unroll
    for (int i = 0; i < 4; ++i) {
      const int qrow = q0 + wid * 16 + g * 4 + i;
      attn[((size_t)(bh >> 4) * 4096 + qrow) * 1024 + (bh & 15) * 64 + e] =
          __float2bfloat16(accO[nt][i] / lrow[i]);
    }
  }
}

// ---------------- output projection GEMM ----------------

__global__ __launch_bounds__(256) void k_gemm_out(
    const hbf* __restrict__ A, const hbf* __restrict__ Bw,
    const float* __restrict__ bp, float* __restrict__ out) {
  __shared__ __align__(16) hbf sA[128 * 64];
  __shared__ __align__(16) hbf sB[128 * 64];
  const int tid = threadIdx.x;
  const int lane = tid & 63, wid = tid >> 6;
  const int m0 = blockIdx.x * 128, n0 = blockIdx.y * 128;
  const int g = lane >> 4, cl = lane & 15;

  const f32x4 fz = {0.f, 0.f, 0.f, 0.f};
  f32x4 acc[4][4];
#pragma unroll
  for (int a = 0; a < 4; ++a)
#pragma unroll
    for (int b = 0; b < 4; ++b) acc[a][b] = fz;

  const int srow = wid * 32 + (lane >> 3);
  const int scol = (lane & 7) * 8;

  for (int kt = 0; kt < 16; ++kt) {
    const int k0 = kt * 64;
#pragma unroll
    for (int t = 0; t < 4; ++t) {
      const int r = srow + t * 8;
      gload_lds16(A + (size_t)(m0 + r) * 1024 + k0 + scol, sA + (wid * 32 + t * 8) * 64);
      gload_lds16(Bw + (size_t)(n0 + r) * 1024 + k0 + scol, sB + (wid * 32 + t * 8) * 64);
    }
    __syncthreads();
#pragma unroll
    for (int ks = 0; ks < 2; ++ks) {
      const int ko = ks * 32 + g * 8;
      bf16x8 af[4], bfr[4];
#pragma unroll
      for (int rt = 0; rt < 4; ++rt)
        af[rt] = *reinterpret_cast<const bf16x8*>(sA + ((wid & 1) * 64 + rt * 16 + cl) * 64 + ko);
#pragma unroll
      for (int ct = 0; ct < 4; ++ct)
        bfr[ct] = *reinterpret_cast<const bf16x8*>(sB + ((wid >> 1) * 64 + ct * 16 + cl) * 64 + ko);
#pragma unroll
      for (int rt = 0; rt < 4; ++rt)
#pragma unroll
        for (int ct = 0; ct < 4; ++ct)
          acc[rt][ct] = __builtin_amdgcn_mfma_f32_16x16x32_bf16(af[rt], bfr[ct], acc[rt][ct], 0, 0, 0);
    }
    __syncthreads();
  }

#pragma unroll
  for (int rt = 0; rt < 4; ++rt)
#pragma unroll
    for (int ct = 0; ct < 4; ++ct) {
      const int colg = n0 + (wid >> 1) * 64 + ct * 16 + cl;
      const float bi = bp[colg];
#pragma unroll
      for (int i = 0; i < 4; ++i) {
        const int rowg = m0 + (wid & 1) * 64 + rt * 16 + g * 4 + i;
        out[(size_t)rowg * 1024 + colg] = acc[rt][ct][i] + bi;
      }
    }
}

// ---------------- launcher ----------------

extern "C" void kernel_launch(void* const* d_in, const int* in_sizes, int n_in,
                              void* d_out, int out_size, void* d_ws, size_t ws_size,
                              hipStream_t stream) {
  const float* x  = (const float*)d_in[0];
  const float* Wq = (const float*)d_in[1];
  const float* Wk = (const float*)d_in[2];
  const float* Wv = (const float*)d_in[3];
  const float* bq = (const float*)d_in[4];
  const float* bk = (const float*)d_in[5];
  const float* bv = (const float*)d_in[6];
  const float* Wp = (const float*)d_in[7];
  const float* bp = (const float*)d_in[8];
  float* out = (float*)d_out;

  char* ws = (char*)d_ws;
  hbf*   xb    = (hbf*)ws;                                   // 16 MiB (reused as attn_out)
  hbf*   Wt    = (hbf*)(ws + 16777216);                      // 6 MiB
  hbf*   Wpt   = (hbf*)(ws + 16777216 + 6291456);            // 2 MiB
  float* biasc = (float*)(ws + 16777216 + 6291456 + 2097152);// 12 KiB (+pad)
  hbf*   qkv   = (hbf*)(ws + 16777216 + 6291456 + 2097152 + 16384); // 48 MiB
  hbf*   attn  = xb;

  k_cvt_x   <<<8192,  256, 0, stream>>>(x, xb);
  k_cvt_w   <<<12288, 256, 0, stream>>>(Wq, Wk, Wv, Wt);
  k_cvt_bias<<<12,    256, 0, stream>>>(bq, bk, bv, biasc);
  k_cvt_wp  <<<4096,  256, 0, stream>>>(Wp, Wpt);

  dim3 g1(64, 24); k_gemm_qkv<<<g1, 256, 0, stream>>>(xb, Wt, biasc, qkv);
  dim3 g2(32, 64); k_flash   <<<g2, 256, 0, stream>>>(qkv, attn);
  dim3 g3(64, 8);  k_gemm_out<<<g3, 256, 0, stream>>>(attn, Wpt, bp, out);
}

// Round 5
// 299.962 us; speedup vs baseline: 2.2460x; 1.2012x over previous
//
#include <hip/hip_runtime.h>
#include <hip/hip_bf16.h>
#include <stdint.h>

// B=2, T=4096, D=1024, H=16, HS=64. Pipeline:
// cvt -> GEMM qkv (bf16 MFMA) -> flash attn (swapped QK^T: lane-local softmax
// with cross-g shfl reduce, bpermute P redistribution, defer-rescale, dbuf
// swizzled K/V) -> GEMM out.

typedef __bf16 bf16x8 __attribute__((ext_vector_type(8)));
typedef float f32x4 __attribute__((ext_vector_type(4)));
typedef __attribute__((address_space(1))) void gvoid_t;
typedef __attribute__((address_space(3))) void lvoid_t;

using hbf = __hip_bfloat16;

#define QSCALE (0.125f * 1.44269504088896f)  // 1/sqrt(HS) * log2(e)

static __device__ __forceinline__ void gload_lds16(const void* g, void* l) {
  __builtin_amdgcn_global_load_lds((gvoid_t*)g, (lvoid_t*)l, 16, 0, 0);
}

static __device__ __forceinline__ uint16_t b2u(float x) {
  hbf h = __float2bfloat16(x);
  return *reinterpret_cast<uint16_t*>(&h);
}

// ---------------- converters ----------------

__global__ void k_cvt_x(const float* __restrict__ x, hbf* __restrict__ xb) {
  int i = (blockIdx.x * 256 + threadIdx.x) * 4;
  float4 v = *reinterpret_cast<const float4*>(x + i);
  hbf h[4] = {__float2bfloat16(v.x), __float2bfloat16(v.y),
              __float2bfloat16(v.z), __float2bfloat16(v.w)};
  *reinterpret_cast<ushort4*>(xb + i) = *reinterpret_cast<ushort4*>(h);
}

__global__ void k_cvt_w(const float* __restrict__ Wq, const float* __restrict__ Wk,
                        const float* __restrict__ Wv, hbf* __restrict__ Wt) {
  int idx = blockIdx.x * 256 + threadIdx.x;   // 3072*1024
  int d = idx & 1023, r = idx >> 10;
  int m = r >> 10, rem = r & 1023;
  int h = rem >> 6, e = rem & 63;
  const float* W = (m == 0) ? Wq : (m == 1) ? Wk : Wv;
  float v = W[(h << 10 | d) * 64 + e];
  if (m == 0) v *= QSCALE;
  Wt[idx] = __float2bfloat16(v);
}

__global__ void k_cvt_bias(const float* __restrict__ bq, const float* __restrict__ bk,
                           const float* __restrict__ bv, float* __restrict__ biasc) {
  int r = blockIdx.x * 256 + threadIdx.x;     // 0..3071
  int m = r >> 10, rem = r & 1023;
  const float* bsrc = (m == 0) ? bq : (m == 1) ? bk : bv;
  float v = bsrc[rem];
  if (m == 0) v *= QSCALE;
  biasc[r] = v;
}

__global__ void k_cvt_wp(const float* __restrict__ Wp, hbf* __restrict__ Wpt) {
  int idx = blockIdx.x * 256 + threadIdx.x;   // 1024*1024
  int o = idx >> 10, d = idx & 1023;
  Wpt[idx] = __float2bfloat16(Wp[(d << 10) + o]);
}

// ---------------- QKV projection GEMM ----------------

__global__ __launch_bounds__(256) void k_gemm_qkv(
    const hbf* __restrict__ A, const hbf* __restrict__ Bw,
    const float* __restrict__ biasc, hbf* __restrict__ qkv) {
  __shared__ __align__(16) hbf sA[128 * 64];
  __shared__ __align__(16) hbf sB[128 * 64];
  const int tid = threadIdx.x;
  const int lane = tid & 63, wid = tid >> 6;
  const int m0 = blockIdx.x * 128, n0 = blockIdx.y * 128;
  const int g = lane >> 4, cl = lane & 15;

  const f32x4 fz = {0.f, 0.f, 0.f, 0.f};
  f32x4 acc[4][4];
#pragma unroll
  for (int a = 0; a < 4; ++a)
#pragma unroll
    for (int b = 0; b < 4; ++b) acc[a][b] = fz;

  const int srow = wid * 32 + (lane >> 3);
  const int scol = (lane & 7) * 8;

  for (int kt = 0; kt < 16; ++kt) {
    const int k0 = kt * 64;
#pragma unroll
    for (int t = 0; t < 4; ++t) {
      const int r = srow + t * 8;
      gload_lds16(A + (size_t)(m0 + r) * 1024 + k0 + scol, sA + (wid * 32 + t * 8) * 64);
      gload_lds16(Bw + (size_t)(n0 + r) * 1024 + k0 + scol, sB + (wid * 32 + t * 8) * 64);
    }
    __syncthreads();
#pragma unroll
    for (int ks = 0; ks < 2; ++ks) {
      const int ko = ks * 32 + g * 8;
      bf16x8 af[4], bfr[4];
#pragma unroll
      for (int rt = 0; rt < 4; ++rt)
        af[rt] = *reinterpret_cast<const bf16x8*>(sA + ((wid & 1) * 64 + rt * 16 + cl) * 64 + ko);
#pragma unroll
      for (int ct = 0; ct < 4; ++ct)
        bfr[ct] = *reinterpret_cast<const bf16x8*>(sB + ((wid >> 1) * 64 + ct * 16 + cl) * 64 + ko);
#pragma unroll
      for (int rt = 0; rt < 4; ++rt)
#pragma unroll
        for (int ct = 0; ct < 4; ++ct)
          acc[rt][ct] = __builtin_amdgcn_mfma_f32_16x16x32_bf16(af[rt], bfr[ct], acc[rt][ct], 0, 0, 0);
    }
    __syncthreads();
  }

#pragma unroll
  for (int rt = 0; rt < 4; ++rt)
#pragma unroll
    for (int ct = 0; ct < 4; ++ct) {
      const int colg = n0 + (wid >> 1) * 64 + ct * 16 + cl;
      const int mi = colg >> 10, rem = colg & 1023;
      const int h = rem >> 6, e = rem & 63;
      const float bi = biasc[colg];
#pragma unroll
      for (int i = 0; i < 4; ++i) {
        const int rowg = m0 + (wid & 1) * 64 + rt * 16 + g * 4 + i;
        const int b = rowg >> 12, t = rowg & 4095;
        qkv[(((size_t)mi * 32 + b * 16 + h) * 4096 + t) * 64 + e] =
            __float2bfloat16(acc[rt][ct][i] + bi);
      }
    }
}

// ---------------- flash attention ----------------
// grid (bh=32, 64); qt = 63 - blockIdx.y. 4 waves x 16 q-rows, KV tiles of 64.
// Swapped QK^T: accS = mfma(K, Q) holds S^T; lane (g,cl) owns q-row cl with
// kv = nt*16+g*4+i (16 of 64) -> row stats = in-reg tree + shfl_xor(16,32)
// across the 4 g-lanes of the row. Defer-rescale (THR=8, exp2 domain).
// P^T -> bf16 pack -> ds_bpermute into PV B-frag; PV = mfma(V^T, P^T).
// K: XOR-swizzled via global_load_lds; V: transposed+swizzled, T14 reg-staged.

__global__ __launch_bounds__(256) void k_flash(
    const hbf* __restrict__ qkv, hbf* __restrict__ attn) {
  __shared__ __align__(16) __bf16 sK[2][64 * 64];
  __shared__ __align__(16) __bf16 sV[2][64 * 64];
  const int tid = threadIdx.x, lane = tid & 63, wid = tid >> 6;
  const int g = lane >> 4, cl = lane & 15;
  const int bh = blockIdx.x;
  const int qt = (int)gridDim.y - 1 - (int)blockIdx.y;
  const int q0 = qt * 64;
  const hbf* Q  = qkv + (size_t)bh * (4096 * 64);
  const hbf* Kp = qkv + (size_t)(32 + bh) * (4096 * 64);
  const hbf* Vp = qkv + (size_t)(64 + bh) * (4096 * 64);
  const float NEG_INF = -__builtin_inff();

  const int koff = (wid * 16 + (lane >> 3)) * 64 + (((lane & 7) ^ (lane >> 3)) * 8);
  const int vr = tid >> 2, vc0 = (tid & 3) * 16;
  const int vgoff = vr * 64 + vc0;

  bf16x8 aq[2];
#pragma unroll
  for (int ks = 0; ks < 2; ++ks)
    aq[ks] = *reinterpret_cast<const bf16x8*>(Q + (size_t)(q0 + wid * 16 + cl) * 64 + ks * 32 + g * 8);

  const f32x4 fz = {0.f, 0.f, 0.f, 0.f};
  f32x4 accO[4];
#pragma unroll
  for (int nt = 0; nt < 4; ++nt) accO[nt] = fz;
  float mrow = NEG_INF, lrow = 0.f;   // per-lane copy of row (cl) stats

  auto vwrite = [&](__bf16* dst, bf16x8 a, bf16x8 b) {
#pragma unroll
    for (int u = 0; u < 8; ++u) {
      const int e = vc0 + u;
      dst[e * 64 + (((vr >> 3) ^ (e & 7) ^ ((e >> 3) & 7)) * 8) + (vr & 7)] = a[u];
    }
#pragma unroll
    for (int u = 8; u < 16; ++u) {
      const int e = vc0 + u;
      dst[e * 64 + (((vr >> 3) ^ (e & 7) ^ ((e >> 3) & 7)) * 8) + (vr & 7)] = b[u - 8];
    }
  };

  // prologue: stage tile 0 into buf 0
  gload_lds16(Kp + koff,       &sK[0][wid * 1024]);
  gload_lds16(Kp + koff + 512, &sK[0][wid * 1024 + 512]);
  {
    bf16x8 a = *reinterpret_cast<const bf16x8*>(Vp + vgoff);
    bf16x8 b = *reinterpret_cast<const bf16x8*>(Vp + vgoff + 8);
    vwrite(sV[0], a, b);
  }
  __syncthreads();

  const int aA = (((g & 1) * 32) + cl) << 2;  // bpermute byte addr: lane (g&1)*2*16+cl
  const int aB = aA + 64;                     // +16 lanes
  const bool ghi = (g & 2) != 0;

  int buf = 0;
  for (int j = 0; j <= qt; ++j) {
    bf16x8 va, vb;
    if (j < qt) {  // prefetch tile j+1: K -> LDS DMA, V -> regs (T14 split)
      const hbf* Kg = Kp + (size_t)(j + 1) * 4096;
      gload_lds16(Kg + koff,       &sK[buf ^ 1][wid * 1024]);
      gload_lds16(Kg + koff + 512, &sK[buf ^ 1][wid * 1024 + 512]);
      const hbf* Vg = Vp + (size_t)(j + 1) * 4096 + vgoff;
      va = *reinterpret_cast<const bf16x8*>(Vg);
      vb = *reinterpret_cast<const bf16x8*>(Vg + 8);
    }

    // S^T = K Q^T : lane holds q-row cl, kv = nt*16 + g*4 + i
    const __bf16* sKb = sK[buf];
    f32x4 accS[4];
#pragma unroll
    for (int nt = 0; nt < 4; ++nt) {
      f32x4 s = fz;
#pragma unroll
      for (int ks = 0; ks < 2; ++ks) {
        bf16x8 bk = *reinterpret_cast<const bf16x8*>(
            sKb + (nt * 16 + cl) * 64 + (((ks * 4 + g) ^ (cl & 7)) * 8));
        s = __builtin_amdgcn_mfma_f32_16x16x32_bf16(bk, aq[ks], s, 0, 0, 0);
      }
      accS[nt] = s;
    }
    if (j == qt) {  // causal: mask kv > q_l (q_l = wid*16+cl)
      const int ql = wid * 16 + cl;
#pragma unroll
      for (int nt = 0; nt < 4; ++nt)
#pragma unroll
        for (int i = 0; i < 4; ++i)
          if (nt * 16 + g * 4 + i > ql) accS[nt][i] = NEG_INF;
    }

    // row stats: in-reg tree over own 16 + cross-g reduce (lanes cl+16k share row cl)
    float m0 = fmaxf(fmaxf(accS[0][0], accS[0][1]), fmaxf(accS[0][2], accS[0][3]));
    float m1 = fmaxf(fmaxf(accS[1][0], accS[1][1]), fmaxf(accS[1][2], accS[1][3]));
    float m2 = fmaxf(fmaxf(accS[2][0], accS[2][1]), fmaxf(accS[2][2], accS[2][3]));
    float m3 = fmaxf(fmaxf(accS[3][0], accS[3][1]), fmaxf(accS[3][2], accS[3][3]));
    float pmax = fmaxf(fmaxf(m0, m1), fmaxf(m2, m3));
    pmax = fmaxf(pmax, __shfl_xor(pmax, 16));
    pmax = fmaxf(pmax, __shfl_xor(pmax, 32));

    if (!__all(pmax - mrow <= 8.f)) {  // defer-rescale (T13)
      const float mn = fmaxf(mrow, pmax);
      const float corr = __builtin_amdgcn_exp2f(mrow - mn);
      mrow = mn;
      lrow *= corr;
#pragma unroll
      for (int nt = 0; nt < 4; ++nt)
#pragma unroll
        for (int i = 0; i < 4; ++i) accO[nt][i] *= corr;
    }

    float p[16];
#pragma unroll
    for (int nt = 0; nt < 4; ++nt)
#pragma unroll
      for (int i = 0; i < 4; ++i)
        p[nt * 4 + i] = __builtin_amdgcn_exp2f(accS[nt][i] - mrow);
    const float s0 = (p[0] + p[1]) + (p[2] + p[3]);
    const float s1 = (p[4] + p[5]) + (p[6] + p[7]);
    const float s2 = (p[8] + p[9]) + (p[10] + p[11]);
    const float s3 = (p[12] + p[13]) + (p[14] + p[15]);
    float rs = (s0 + s1) + (s2 + s3);
    rs += __shfl_xor(rs, 16);
    rs += __shfl_xor(rs, 32);
    lrow += rs;

    // pack P^T rows (kv ascending) into dwords: pk[nt][d] = (i=2d, i=2d+1)
    uint32_t pk[4][2];
#pragma unroll
    for (int nt = 0; nt < 4; ++nt)
#pragma unroll
      for (int d = 0; d < 2; ++d)
        pk[nt][d] = (uint32_t)b2u(p[nt * 4 + 2 * d]) |
                    ((uint32_t)b2u(p[nt * 4 + 2 * d + 1]) << 16);

    // PV^T: B-frag dword w <- src lane ((g&1)*2+(w>>1))*16+cl, reg nt=2ks+(g>>1)
    const __bf16* sVb = sV[buf];
#pragma unroll
    for (int ks = 0; ks < 2; ++ks) {
      const int n0i = ks * 2, n1i = n0i + 1;
      union { uint32_t u[4]; bf16x8 v; } bP;
      {
        const int t0 = __builtin_amdgcn_ds_bpermute(aA, (int)pk[n0i][0]);
        const int t1 = __builtin_amdgcn_ds_bpermute(aA, (int)pk[n1i][0]);
        bP.u[0] = (uint32_t)(ghi ? t1 : t0);
        const int t2 = __builtin_amdgcn_ds_bpermute(aA, (int)pk[n0i][1]);
        const int t3 = __builtin_amdgcn_ds_bpermute(aA, (int)pk[n1i][1]);
        bP.u[1] = (uint32_t)(ghi ? t3 : t2);
        const int t4 = __builtin_amdgcn_ds_bpermute(aB, (int)pk[n0i][0]);
        const int t5 = __builtin_amdgcn_ds_bpermute(aB, (int)pk[n1i][0]);
        bP.u[2] = (uint32_t)(ghi ? t5 : t4);
        const int t6 = __builtin_amdgcn_ds_bpermute(aB, (int)pk[n0i][1]);
        const int t7 = __builtin_amdgcn_ds_bpermute(aB, (int)pk[n1i][1]);
        bP.u[3] = (uint32_t)(ghi ? t7 : t6);
      }
#pragma unroll
      for (int nt = 0; nt < 4; ++nt) {
        const int e = nt * 16 + cl;
        const int chunk = (ks * 4 + g) ^ (cl & 7) ^ ((2 * nt + (cl >> 3)) & 7);
        bf16x8 bv = *reinterpret_cast<const bf16x8*>(sVb + e * 64 + chunk * 8);
        accO[nt] = __builtin_amdgcn_mfma_f32_16x16x32_bf16(bv, bP.v, accO[nt], 0, 0, 0);
      }
    }

    if (j < qt) vwrite(sV[buf ^ 1], va, vb);
    __syncthreads();  // drains K DMA + V writes; all waves done with buf
    buf ^= 1;
  }

  // epilogue: accO^T holds [e = nt*16+g*4+i][q = cl]; 8B packed stores
  const float inv = 1.0f / lrow;
  const int qrow = q0 + wid * 16 + cl;
  hbf* arow = attn + ((size_t)(bh >> 4) * 4096 + qrow) * 1024 + (bh & 15) * 64;
#pragma unroll
  for (int nt = 0; nt < 4; ++nt) {
    ushort4 o;
    o.x = b2u(accO[nt][0] * inv);
    o.y = b2u(accO[nt][1] * inv);
    o.z = b2u(accO[nt][2] * inv);
    o.w = b2u(accO[nt][3] * inv);
    *reinterpret_cast<ushort4*>(arow + nt * 16 + g * 4) = o;
  }
}

// ---------------- output projection GEMM ----------------

__global__ __launch_bounds__(256) void k_gemm_out(
    const hbf* __restrict__ A, const hbf* __restrict__ Bw,
    const float* __restrict__ bp, float* __restrict__ out) {
  __shared__ __align__(16) hbf sA[128 * 64];
  __shared__ __align__(16) hbf sB[128 * 64];
  const int tid = threadIdx.x;
  const int lane = tid & 63, wid = tid >> 6;
  const int m0 = blockIdx.x * 128, n0 = blockIdx.y * 128;
  const int g = lane >> 4, cl = lane & 15;

  const f32x4 fz = {0.f, 0.f, 0.f, 0.f};
  f32x4 acc[4][4];
#pragma unroll
  for (int a = 0; a < 4; ++a)
#pragma unroll
    for (int b = 0; b < 4; ++b) acc[a][b] = fz;

  const int srow = wid * 32 + (lane >> 3);
  const int scol = (lane & 7) * 8;

  for (int kt = 0; kt < 16; ++kt) {
    const int k0 = kt * 64;
#pragma unroll
    for (int t = 0; t < 4; ++t) {
      const int r = srow + t * 8;
      gload_lds16(A + (size_t)(m0 + r) * 1024 + k0 + scol, sA + (wid * 32 + t * 8) * 64);
      gload_lds16(Bw + (size_t)(n0 + r) * 1024 + k0 + scol, sB + (wid * 32 + t * 8) * 64);
    }
    __syncthreads();
#pragma unroll
    for (int ks = 0; ks < 2; ++ks) {
      const int ko = ks * 32 + g * 8;
      bf16x8 af[4], bfr[4];
#pragma unroll
      for (int rt = 0; rt < 4; ++rt)
        af[rt] = *reinterpret_cast<const bf16x8*>(sA + ((wid & 1) * 64 + rt * 16 + cl) * 64 + ko);
#pragma unroll
      for (int ct = 0; ct < 4; ++ct)
        bfr[ct] = *reinterpret_cast<const bf16x8*>(sB + ((wid >> 1) * 64 + ct * 16 + cl) * 64 + ko);
#pragma unroll
      for (int rt = 0; rt < 4; ++rt)
#pragma unroll
        for (int ct = 0; ct < 4; ++ct)
          acc[rt][ct] = __builtin_amdgcn_mfma_f32_16x16x32_bf16(af[rt], bfr[ct], acc[rt][ct], 0, 0, 0);
    }
    __syncthreads();
  }

#pragma unroll
  for (int rt = 0; rt < 4; ++rt)
#pragma unroll
    for (int ct = 0; ct < 4; ++ct) {
      const int colg = n0 + (wid >> 1) * 64 + ct * 16 + cl;
      const float bi = bp[colg];
#pragma unroll
      for (int i = 0; i < 4; ++i) {
        const int rowg = m0 + (wid & 1) * 64 + rt * 16 + g * 4 + i;
        out[(size_t)rowg * 1024 + colg] = acc[rt][ct][i] + bi;
      }
    }
}

// ---------------- launcher ----------------

extern "C" void kernel_launch(void* const* d_in, const int* in_sizes, int n_in,
                              void* d_out, int out_size, void* d_ws, size_t ws_size,
                              hipStream_t stream) {
  const float* x  = (const float*)d_in[0];
  const float* Wq = (const float*)d_in[1];
  const float* Wk = (const float*)d_in[2];
  const float* Wv = (const float*)d_in[3];
  const float* bq = (const float*)d_in[4];
  const float* bk = (const float*)d_in[5];
  const float* bv = (const float*)d_in[6];
  const float* Wp = (const float*)d_in[7];
  const float* bp = (const float*)d_in[8];
  float* out = (float*)d_out;

  char* ws = (char*)d_ws;
  hbf*   xb    = (hbf*)ws;                                   // 16 MiB (reused as attn_out)
  hbf*   Wt    = (hbf*)(ws + 16777216);                      // 6 MiB
  hbf*   Wpt   = (hbf*)(ws + 16777216 + 6291456);            // 2 MiB
  float* biasc = (float*)(ws + 16777216 + 6291456 + 2097152);// 12 KiB (+pad)
  hbf*   qkv   = (hbf*)(ws + 16777216 + 6291456 + 2097152 + 16384); // 48 MiB
  hbf*   attn  = xb;

  k_cvt_x   <<<8192,  256, 0, stream>>>(x, xb);
  k_cvt_w   <<<12288, 256, 0, stream>>>(Wq, Wk, Wv, Wt);
  k_cvt_bias<<<12,    256, 0, stream>>>(bq, bk, bv, biasc);
  k_cvt_wp  <<<4096,  256, 0, stream>>>(Wp, Wpt);

  dim3 g1(64, 24); k_gemm_qkv<<<g1, 256, 0, stream>>>(xb, Wt, biasc, qkv);
  dim3 g2(32, 64); k_flash   <<<g2, 256, 0, stream>>>(qkv, attn);
  dim3 g3(64, 8);  k_gemm_out<<<g3, 256, 0, stream>>>(attn, Wpt, bp, out);
}